// Round 1
// baseline (200.388 us; speedup 1.0000x reference)
//
#include <hip/hip_runtime.h>
#include <math.h>

#define BB 32
#define HH 56
#define WW 56
#define CC 256
#define NPIX (BB * HH * WW)   // 100352 pixels; CC=256 floats per pixel

// Kernel 1: per-pixel channel mean + max.
// One wave (64 lanes) per pixel; each lane loads float4 (4 channels).
__global__ __launch_bounds__(256) void pool_kernel(const float* __restrict__ x,
                                                   float* __restrict__ pooled) {
    int pix  = blockIdx.x * 4 + (threadIdx.x >> 6);
    int lane = threadIdx.x & 63;
    const float4* x4 = (const float4*)x;
    float4 v = x4[(size_t)pix * 64 + lane];
    float s = v.x + v.y + v.z + v.w;
    float m = fmaxf(fmaxf(v.x, v.y), fmaxf(v.z, v.w));
#pragma unroll
    for (int o = 32; o > 0; o >>= 1) {
        s += __shfl_down(s, o, 64);
        m = fmaxf(m, __shfl_down(m, o, 64));
    }
    if (lane == 0) {
        pooled[pix * 2]     = s * (1.0f / 256.0f);
        pooled[pix * 2 + 1] = m;
    }
}

// Kernel 2: 7x7 'SAME' conv (2->1 ch, HWIO weights) + bias + sigmoid.
// One thread per pixel; pooled map (0.8 MB) is L2-resident.
__global__ __launch_bounds__(256) void conv_kernel(const float* __restrict__ pooled,
                                                   const float* __restrict__ cw,
                                                   const float* __restrict__ cb,
                                                   float* __restrict__ attn) {
    int idx = blockIdx.x * 256 + threadIdx.x;
    if (idx >= NPIX) return;
    int b  = idx / (HH * WW);
    int hw = idx % (HH * WW);
    int h  = hw / WW;
    int w  = hw % WW;
    float acc = cb[0];
    const float* base = pooled + (size_t)b * HH * WW * 2;
#pragma unroll
    for (int dh = 0; dh < 7; ++dh) {
        int ih = h + dh - 3;
        if (ih < 0 || ih >= HH) continue;
#pragma unroll
        for (int dw = 0; dw < 7; ++dw) {
            int iw = w + dw - 3;
            if (iw < 0 || iw >= WW) continue;
            const float* p = base + (ih * WW + iw) * 2;
            const float* k = cw + (dh * 7 + dw) * 2;
            acc = fmaf(p[0], k[0], acc);
            acc = fmaf(p[1], k[1], acc);
        }
    }
    attn[idx] = 1.0f / (1.0f + expf(-acc));
}

// Kernel 3: out = x * attn (broadcast over 256 channels), float4 grid-stride.
__global__ __launch_bounds__(256) void scale_kernel(const float* __restrict__ x,
                                                    const float* __restrict__ attn,
                                                    float* __restrict__ out) {
    size_t i = (size_t)blockIdx.x * 256 + threadIdx.x;  // float4 index
    const float4* x4 = (const float4*)x;
    float4* o4 = (float4*)out;
    float a = attn[i >> 6];   // 64 float4s per pixel
    float4 v = x4[i];
    v.x *= a; v.y *= a; v.z *= a; v.w *= a;
    o4[i] = v;
}

extern "C" void kernel_launch(void* const* d_in, const int* in_sizes, int n_in,
                              void* d_out, int out_size, void* d_ws, size_t ws_size,
                              hipStream_t stream) {
    const float* x  = (const float*)d_in[0];
    const float* cw = (const float*)d_in[1];   // [7,7,2,1] HWIO
    const float* cb = (const float*)d_in[2];   // [1]
    float* out = (float*)d_out;

    float* pooled = (float*)d_ws;              // NPIX*2 floats
    float* attn   = pooled + (size_t)NPIX * 2; // NPIX floats

    // 1) pool: NPIX waves, 4 waves/block
    pool_kernel<<<NPIX / 4, 256, 0, stream>>>(x, pooled);
    // 2) conv+sigmoid: one thread per pixel
    conv_kernel<<<(NPIX + 255) / 256, 256, 0, stream>>>(pooled, cw, cb, attn);
    // 3) scale: NPIX*64 float4s, 256 threads/block
    scale_kernel<<<NPIX / 4, 256, 0, stream>>>(x, attn, out);
}